// Round 15
// baseline (286.184 us; speedup 1.0000x reference)
//
#include <hip/hip_runtime.h>

#define NUM_COND 16
#define FDIM 128
#define EPS 1e-5f
#define WPB 4            // waves per stats block (4 x 16KB wave-private regions = 64KB)
#define NSLOT 8          // prefetch / RMW-chain depth per wave
#define PB 4160          // floats per partial: s1[2048] s2[2048] cnt[WPB*16]
#define MAXNB 512

typedef float __attribute__((ext_vector_type(4))) f4v;
__device__ __forceinline__ void nt_store4(float4* p, const float4& v) {
    f4v t = { v.x, v.y, v.z, v.w };
    __builtin_nontemporal_store(t, (f4v*)p);
}

// Stats: one ROW per wave (lane covers features 2*lane, 2*lane+1 as float2).
// Wave-private 16KB LDS region, NON-ATOMIC read-modify-write (ds_read_b64 /
// v_add / ds_write_b64). DS ops are in-order within a wave -> consecutive
// same-label rows accumulate correctly without atomics. Addresses are
// lab*512 + lane*8 bytes -> contiguous 512B per wave-op -> conflict-free.
// Geometry = R6/R9 verified optimum (256 thr, WPB=4, 2 blocks/CU).
// NSLOT=8 independent RMW chains per wave (R14 measured stats at 46.8us,
// ~7us above its flat-read floor; deeper pipeline is the only lever that
// has measured positive on this structure: 4->6 gave -3.2us).
// Loads REGULAR (allocating) so x stays in the 256MB L3; y written NT.
__global__ __launch_bounds__(256) void cbn_stats_kernel(
    const float* __restrict__ x, const int* __restrict__ labels,
    float* __restrict__ ws, int N, int chunk)
{
    __shared__ float acc[WPB][4096];     // per wave: s1[16][128] then s2[16][128]
    const int t = threadIdx.x;
    const int w = t >> 6;
    const int lane = t & 63;

    // zero own region only (wave-private -> no barrier needed before use)
    {
        float4* z = (float4*)acc[w];
        for (int i = lane; i < 1024; i += 64) z[i] = make_float4(0.f, 0.f, 0.f, 0.f);
    }

    const int rbeg = blockIdx.x * chunk;
    const int rend = min(N, rbeg + chunk);
    const float2* x2 = (const float2*)x;
    float2* r1 = (float2*)acc[w];          // s1 rows (float2 units)
    float2* r2 = ((float2*)acc[w]) + 1024; // s2 rows

    int cnt = 0;
    float2 v0, v1, v2, v3, v4, v5, v6, v7;
    int lb0 = 0, lb1 = 0, lb2 = 0, lb3 = 0, lb4 = 0, lb5 = 0, lb6 = 0, lb7 = 0;
    v0 = v1 = v2 = v3 = v4 = v5 = v6 = v7 = make_float2(0.f, 0.f);

#define LOADSLOT(S, R)                                              \
    {   const int r_ = (R);                                         \
        if (r_ < rend) {                                            \
            v##S = x2[(size_t)r_ * 64 + lane];                      \
            lb##S = labels[r_];                                     \
        }                                                           \
    }

#define PROCSLOT(S, R)                                              \
    {   const int r_ = (R);                                         \
        if (r_ < rend) {                                            \
            const int o_ = lb##S * 64 + lane;                       \
            float2 o1 = r1[o_];                                     \
            float2 o2 = r2[o_];                                     \
            o1.x += v##S.x;                  o1.y += v##S.y;        \
            o2.x = fmaf(v##S.x, v##S.x, o2.x);                      \
            o2.y = fmaf(v##S.y, v##S.y, o2.y);                      \
            r1[o_] = o1;                                            \
            r2[o_] = o2;                                            \
            cnt += ((lane & 15) == lb##S) ? 1 : 0;                  \
        }                                                           \
    }

    int r = rbeg + w;
    LOADSLOT(0, r)
    LOADSLOT(1, r + WPB)
    LOADSLOT(2, r + 2 * WPB)
    LOADSLOT(3, r + 3 * WPB)
    LOADSLOT(4, r + 4 * WPB)
    LOADSLOT(5, r + 5 * WPB)
    LOADSLOT(6, r + 6 * WPB)
    LOADSLOT(7, r + 7 * WPB)

    for (; r < rend; r += NSLOT * WPB) {
        PROCSLOT(0, r)
        LOADSLOT(0, r + 8 * WPB)
        PROCSLOT(1, r + WPB)
        LOADSLOT(1, r + 9 * WPB)
        PROCSLOT(2, r + 2 * WPB)
        LOADSLOT(2, r + 10 * WPB)
        PROCSLOT(3, r + 3 * WPB)
        LOADSLOT(3, r + 11 * WPB)
        PROCSLOT(4, r + 4 * WPB)
        LOADSLOT(4, r + 12 * WPB)
        PROCSLOT(5, r + 5 * WPB)
        LOADSLOT(5, r + 13 * WPB)
        PROCSLOT(6, r + 6 * WPB)
        LOADSLOT(6, r + 14 * WPB)
        PROCSLOT(7, r + 7 * WPB)
        LOADSLOT(7, r + 15 * WPB)
    }

    __syncthreads();
    // block flush: sum the 4 wave regions -> one partial per block
    float* out = ws + (size_t)blockIdx.x * PB;
    for (int i = t; i < 4096; i += 256)
        out[i] = acc[0][i] + acc[1][i] + acc[2][i] + acc[3][i];
    // The whole wave processes one row together, so lanes l, l+16, l+32, l+48
    // hold IDENTICAL counts for label l. Take lane<16 directly (no summing —
    // summing the redundant copies was R4's 4x-overcount bug).
    if (lane < 16) out[4096 + w * 16 + lane] = (float)cnt;
}

// Fused reduce+finalize: 8 blocks x 256 thr; thread e (= lab*128+f) sums its
// s1/s2 entries across all nb partials directly (coalesced across threads),
// counts summed by a 64-thread LDS pre-pass. Replaces the two-stage
// reduce->ws2->finalize path (saves the round-trip and one launch).
__global__ __launch_bounds__(256) void cbn_reduce_finalize_kernel(
    const float* __restrict__ ws, const float* __restrict__ gamma,
    const float* __restrict__ beta, float* __restrict__ scale_shift, int nb)
{
    __shared__ float scnt[WPB * 16];
    const int t = threadIdx.x;
    const int e = blockIdx.x * 256 + t;   // 0..2047 = lab*128 + f
    const int lab = e >> 7;

    if (t < WPB * 16) {
        float c = 0.f;
#pragma unroll 8
        for (int b = 0; b < nb; ++b) c += ws[(size_t)b * PB + 4096 + t];
        scnt[t] = c;
    }
    __syncthreads();

    float a1 = 0.f, a2 = 0.f;
#pragma unroll 8
    for (int b = 0; b < nb; ++b) {
        const float* p = ws + (size_t)b * PB;
        a1 += p[e];
        a2 += p[2048 + e];
    }
    float cn = 0.f;
#pragma unroll
    for (int w2 = 0; w2 < WPB; ++w2) cn += scnt[w2 * 16 + lab];
    cn = fmaxf(cn, 1.0f);

    const float mean = a1 / cn;
    const float var  = a2 / cn - mean * mean;
    const float sc = gamma[e] * rsqrtf(var + EPS);
    const float sh = beta[e] - mean * sc;
    scale_shift[e]        = sc;
    scale_shift[2048 + e] = sh;
}

// Apply: x loads regular; y stores NONTEMPORAL so the dead store stream
// doesn't evict x from the 256MB L3. Measured at ~78us for 488MB moved
// (6.2 TB/s) — at the fabric ceiling; structure untouched.
__global__ __launch_bounds__(256) void cbn_apply_kernel(
    const float* __restrict__ x, const int* __restrict__ labels,
    const float* __restrict__ scale_shift, float* __restrict__ y, int N)
{
    __shared__ float4 ssc[NUM_COND * 32];
    __shared__ float4 ssh[NUM_COND * 32];
    const int t = threadIdx.x;
    const float4* ss4 = (const float4*)scale_shift;
    for (int i = t; i < NUM_COND * 32; i += 256) {
        ssc[i] = ss4[i];
        ssh[i] = ss4[512 + i];
    }
    __syncthreads();

    const int f4 = t & 31;
    const int rg = t >> 5;                 // 0..7
    const float4* x4 = (const float4*)x;
    float4* y4 = (float4*)y;

    for (int base = blockIdx.x * 32 + rg; base < N; base += gridDim.x * 32) {
        const int r0 = base;
        int r1 = base + 8, r2 = base + 16, r3 = base + 24;
        const bool k1 = r1 < N, k2 = r2 < N, k3 = r3 < N;
        if (!k1) r1 = r0;  if (!k2) r2 = r0;  if (!k3) r3 = r0;

        const int l0 = labels[r0], l1 = labels[r1], l2 = labels[r2], l3 = labels[r3];
        const float4 v0 = x4[(size_t)r0 * 32 + f4];
        const float4 v1 = x4[(size_t)r1 * 32 + f4];
        const float4 v2 = x4[(size_t)r2 * 32 + f4];
        const float4 v3 = x4[(size_t)r3 * 32 + f4];

        const float4 c0 = ssc[l0 * 32 + f4], h0 = ssh[l0 * 32 + f4];
        const float4 c1 = ssc[l1 * 32 + f4], h1 = ssh[l1 * 32 + f4];
        const float4 c2 = ssc[l2 * 32 + f4], h2 = ssh[l2 * 32 + f4];
        const float4 c3 = ssc[l3 * 32 + f4], h3 = ssh[l3 * 32 + f4];

        float4 o0, o1, o2, o3;
        o0.x = fmaf(v0.x, c0.x, h0.x); o0.y = fmaf(v0.y, c0.y, h0.y);
        o0.z = fmaf(v0.z, c0.z, h0.z); o0.w = fmaf(v0.w, c0.w, h0.w);
        o1.x = fmaf(v1.x, c1.x, h1.x); o1.y = fmaf(v1.y, c1.y, h1.y);
        o1.z = fmaf(v1.z, c1.z, h1.z); o1.w = fmaf(v1.w, c1.w, h1.w);
        o2.x = fmaf(v2.x, c2.x, h2.x); o2.y = fmaf(v2.y, c2.y, h2.y);
        o2.z = fmaf(v2.z, c2.z, h2.z); o2.w = fmaf(v2.w, c2.w, h2.w);
        o3.x = fmaf(v3.x, c3.x, h3.x); o3.y = fmaf(v3.y, c3.y, h3.y);
        o3.z = fmaf(v3.z, c3.z, h3.z); o3.w = fmaf(v3.w, c3.w, h3.w);

        nt_store4(&y4[(size_t)r0 * 32 + f4], o0);
        if (k1) nt_store4(&y4[(size_t)r1 * 32 + f4], o1);
        if (k2) nt_store4(&y4[(size_t)r2 * 32 + f4], o2);
        if (k3) nt_store4(&y4[(size_t)r3 * 32 + f4], o3);
    }
}

extern "C" void kernel_launch(void* const* d_in, const int* in_sizes, int n_in,
                              void* d_out, int out_size, void* d_ws, size_t ws_size,
                              hipStream_t stream)
{
    const float* x      = (const float*)d_in[0];
    const int*   labels = (const int*)d_in[1];
    const float* gamma  = (const float*)d_in[2];
    const float* beta   = (const float*)d_in[3];
    float* y  = (float*)d_out;
    float* ws = (float*)d_ws;
    const int N = in_sizes[1];

    // ws layout: [nb partials][scale/shift 4096]
    const long floats = (long)(ws_size / sizeof(float));
    long avail = floats - 4096;
    int nb = MAXNB;
    if ((long)nb * PB > avail) nb = (int)(avail / PB);
    if (nb < 1) nb = 1;
    const int chunk = (N + nb - 1) / nb;

    float* scale_shift = ws + (size_t)nb * PB;

    cbn_stats_kernel<<<nb, 256, 0, stream>>>(x, labels, ws, N, chunk);
    cbn_reduce_finalize_kernel<<<8, 256, 0, stream>>>(ws, gamma, beta, scale_shift, nb);
    cbn_apply_kernel<<<2048, 256, 0, stream>>>(x, labels, scale_shift, y, N);
}

// Round 16
// 135.670 us; speedup vs baseline: 2.1094x; 2.1094x over previous
//
#include <hip/hip_runtime.h>

#define NUM_COND 16
#define FDIM 128
#define EPS 1e-5f
#define WPB 4            // waves per stats block (4 x 16KB wave-private regions = 64KB)
#define NSLOT 8          // prefetch / RMW-chain depth per wave
#define PB 4160          // floats per partial: s1[2048] s2[2048] cnt[WPB*16]
#define NCHUNK 16
#define MAXNB 512

typedef float __attribute__((ext_vector_type(4))) f4v;
__device__ __forceinline__ void nt_store4(float4* p, const float4& v) {
    f4v t = { v.x, v.y, v.z, v.w };
    __builtin_nontemporal_store(t, (f4v*)p);
}

// Stats: one ROW per wave (lane covers features 2*lane, 2*lane+1 as float2).
// Wave-private 16KB LDS region, NON-ATOMIC read-modify-write (ds_read_b64 /
// v_add / ds_write_b64). DS ops are in-order within a wave -> consecutive
// same-label rows accumulate correctly without atomics. Addresses are
// lab*512 + lane*8 bytes -> contiguous 512B per wave-op -> conflict-free.
// Geometry = R6/R9 verified optimum (256 thr, WPB=4, 2 blocks/CU).
// NSLOT=8 (R15 side-measurement: stats ~40-42us vs 46.8 at NSLOT=6).
// Loads REGULAR (allocating) so x stays in the 256MB L3; y written NT.
__global__ __launch_bounds__(256) void cbn_stats_kernel(
    const float* __restrict__ x, const int* __restrict__ labels,
    float* __restrict__ ws, int N, int chunk)
{
    __shared__ float acc[WPB][4096];     // per wave: s1[16][128] then s2[16][128]
    const int t = threadIdx.x;
    const int w = t >> 6;
    const int lane = t & 63;

    // zero own region only (wave-private -> no barrier needed before use)
    {
        float4* z = (float4*)acc[w];
        for (int i = lane; i < 1024; i += 64) z[i] = make_float4(0.f, 0.f, 0.f, 0.f);
    }

    const int rbeg = blockIdx.x * chunk;
    const int rend = min(N, rbeg + chunk);
    const float2* x2 = (const float2*)x;
    float2* r1 = (float2*)acc[w];          // s1 rows (float2 units)
    float2* r2 = ((float2*)acc[w]) + 1024; // s2 rows

    int cnt = 0;
    float2 v0, v1, v2, v3, v4, v5, v6, v7;
    int lb0 = 0, lb1 = 0, lb2 = 0, lb3 = 0, lb4 = 0, lb5 = 0, lb6 = 0, lb7 = 0;
    v0 = v1 = v2 = v3 = v4 = v5 = v6 = v7 = make_float2(0.f, 0.f);

#define LOADSLOT(S, R)                                              \
    {   const int r_ = (R);                                         \
        if (r_ < rend) {                                            \
            v##S = x2[(size_t)r_ * 64 + lane];                      \
            lb##S = labels[r_];                                     \
        }                                                           \
    }

#define PROCSLOT(S, R)                                              \
    {   const int r_ = (R);                                         \
        if (r_ < rend) {                                            \
            const int o_ = lb##S * 64 + lane;                       \
            float2 o1 = r1[o_];                                     \
            float2 o2 = r2[o_];                                     \
            o1.x += v##S.x;                  o1.y += v##S.y;        \
            o2.x = fmaf(v##S.x, v##S.x, o2.x);                      \
            o2.y = fmaf(v##S.y, v##S.y, o2.y);                      \
            r1[o_] = o1;                                            \
            r2[o_] = o2;                                            \
            cnt += ((lane & 15) == lb##S) ? 1 : 0;                  \
        }                                                           \
    }

    int r = rbeg + w;
    LOADSLOT(0, r)
    LOADSLOT(1, r + WPB)
    LOADSLOT(2, r + 2 * WPB)
    LOADSLOT(3, r + 3 * WPB)
    LOADSLOT(4, r + 4 * WPB)
    LOADSLOT(5, r + 5 * WPB)
    LOADSLOT(6, r + 6 * WPB)
    LOADSLOT(7, r + 7 * WPB)

    for (; r < rend; r += NSLOT * WPB) {
        PROCSLOT(0, r)
        LOADSLOT(0, r + 8 * WPB)
        PROCSLOT(1, r + WPB)
        LOADSLOT(1, r + 9 * WPB)
        PROCSLOT(2, r + 2 * WPB)
        LOADSLOT(2, r + 10 * WPB)
        PROCSLOT(3, r + 3 * WPB)
        LOADSLOT(3, r + 11 * WPB)
        PROCSLOT(4, r + 4 * WPB)
        LOADSLOT(4, r + 12 * WPB)
        PROCSLOT(5, r + 5 * WPB)
        LOADSLOT(5, r + 13 * WPB)
        PROCSLOT(6, r + 6 * WPB)
        LOADSLOT(6, r + 14 * WPB)
        PROCSLOT(7, r + 7 * WPB)
        LOADSLOT(7, r + 15 * WPB)
    }

    __syncthreads();
    // block flush: sum the 4 wave regions -> one partial per block
    float* out = ws + (size_t)blockIdx.x * PB;
    for (int i = t; i < 4096; i += 256)
        out[i] = acc[0][i] + acc[1][i] + acc[2][i] + acc[3][i];
    // The whole wave processes one row together, so lanes l, l+16, l+32, l+48
    // hold IDENTICAL counts for label l. Take lane<16 directly (no summing —
    // summing the redundant copies was R4's 4x-overcount bug).
    if (lane < 16) out[4096 + w * 16 + lane] = (float)cnt;
}

// stage 1 reduce: sum partials in NCHUNK chunks; grid = (ceil(PB/256), NCHUNK)
// = 272 blocks (R15 lesson: the 8-block fused version was 163us latency-bound
// — keep the grid wide).
__global__ __launch_bounds__(256) void cbn_reduce_kernel(
    const float* __restrict__ ws, float* __restrict__ ws2, int nb, int per)
{
    const int e = blockIdx.x * 256 + threadIdx.x;
    if (e >= PB) return;
    const int b0 = blockIdx.y * per;
    const int b1 = min(nb, b0 + per);
    float a = 0.f;
#pragma unroll 8
    for (int b = b0; b < b1; ++b) a += ws[(size_t)b * PB + e];
    ws2[(size_t)blockIdx.y * PB + e] = a;
}

// stage 2: reduce NCHUNK chunk-partials, compute scale/shift (natural layout).
__global__ __launch_bounds__(256) void cbn_finalize_kernel(
    const float* __restrict__ ws2, const float* __restrict__ gamma,
    const float* __restrict__ beta, float* __restrict__ scale_shift)
{
    const int e = blockIdx.x * 256 + threadIdx.x;   // e = lab*128 + f
    const int lab = e >> 7;
    float a1 = 0.f, a2 = 0.f, cn = 0.f;
#pragma unroll
    for (int k = 0; k < NCHUNK; ++k) {
        const float* p = ws2 + (size_t)k * PB;
        a1 += p[e];
        a2 += p[2048 + e];
#pragma unroll
        for (int w2 = 0; w2 < WPB; ++w2)
            cn += p[4096 + w2 * 16 + lab];
    }
    cn = fmaxf(cn, 1.0f);
    const float mean = a1 / cn;
    const float var  = a2 / cn - mean * mean;
    const float sc = gamma[e] * rsqrtf(var + EPS);
    const float sh = beta[e] - mean * sc;
    scale_shift[e]        = sc;
    scale_shift[2048 + e] = sh;
}

// Apply: x loads regular; y stores NONTEMPORAL so the dead store stream
// doesn't evict x from the 256MB L3. Measured at ~78us for 488MB moved
// (6.2 TB/s) — at the fabric ceiling; structure untouched.
__global__ __launch_bounds__(256) void cbn_apply_kernel(
    const float* __restrict__ x, const int* __restrict__ labels,
    const float* __restrict__ scale_shift, float* __restrict__ y, int N)
{
    __shared__ float4 ssc[NUM_COND * 32];
    __shared__ float4 ssh[NUM_COND * 32];
    const int t = threadIdx.x;
    const float4* ss4 = (const float4*)scale_shift;
    for (int i = t; i < NUM_COND * 32; i += 256) {
        ssc[i] = ss4[i];
        ssh[i] = ss4[512 + i];
    }
    __syncthreads();

    const int f4 = t & 31;
    const int rg = t >> 5;                 // 0..7
    const float4* x4 = (const float4*)x;
    float4* y4 = (float4*)y;

    for (int base = blockIdx.x * 32 + rg; base < N; base += gridDim.x * 32) {
        const int r0 = base;
        int r1 = base + 8, r2 = base + 16, r3 = base + 24;
        const bool k1 = r1 < N, k2 = r2 < N, k3 = r3 < N;
        if (!k1) r1 = r0;  if (!k2) r2 = r0;  if (!k3) r3 = r0;

        const int l0 = labels[r0], l1 = labels[r1], l2 = labels[r2], l3 = labels[r3];
        const float4 v0 = x4[(size_t)r0 * 32 + f4];
        const float4 v1 = x4[(size_t)r1 * 32 + f4];
        const float4 v2 = x4[(size_t)r2 * 32 + f4];
        const float4 v3 = x4[(size_t)r3 * 32 + f4];

        const float4 c0 = ssc[l0 * 32 + f4], h0 = ssh[l0 * 32 + f4];
        const float4 c1 = ssc[l1 * 32 + f4], h1 = ssh[l1 * 32 + f4];
        const float4 c2 = ssc[l2 * 32 + f4], h2 = ssh[l2 * 32 + f4];
        const float4 c3 = ssc[l3 * 32 + f4], h3 = ssh[l3 * 32 + f4];

        float4 o0, o1, o2, o3;
        o0.x = fmaf(v0.x, c0.x, h0.x); o0.y = fmaf(v0.y, c0.y, h0.y);
        o0.z = fmaf(v0.z, c0.z, h0.z); o0.w = fmaf(v0.w, c0.w, h0.w);
        o1.x = fmaf(v1.x, c1.x, h1.x); o1.y = fmaf(v1.y, c1.y, h1.y);
        o1.z = fmaf(v1.z, c1.z, h1.z); o1.w = fmaf(v1.w, c1.w, h1.w);
        o2.x = fmaf(v2.x, c2.x, h2.x); o2.y = fmaf(v2.y, c2.y, h2.y);
        o2.z = fmaf(v2.z, c2.z, h2.z); o2.w = fmaf(v2.w, c2.w, h2.w);
        o3.x = fmaf(v3.x, c3.x, h3.x); o3.y = fmaf(v3.y, c3.y, h3.y);
        o3.z = fmaf(v3.z, c3.z, h3.z); o3.w = fmaf(v3.w, c3.w, h3.w);

        nt_store4(&y4[(size_t)r0 * 32 + f4], o0);
        if (k1) nt_store4(&y4[(size_t)r1 * 32 + f4], o1);
        if (k2) nt_store4(&y4[(size_t)r2 * 32 + f4], o2);
        if (k3) nt_store4(&y4[(size_t)r3 * 32 + f4], o3);
    }
}

extern "C" void kernel_launch(void* const* d_in, const int* in_sizes, int n_in,
                              void* d_out, int out_size, void* d_ws, size_t ws_size,
                              hipStream_t stream)
{
    const float* x      = (const float*)d_in[0];
    const int*   labels = (const int*)d_in[1];
    const float* gamma  = (const float*)d_in[2];
    const float* beta   = (const float*)d_in[3];
    float* y  = (float*)d_out;
    float* ws = (float*)d_ws;
    const int N = in_sizes[1];

    // ws layout: [nb partials][NCHUNK chunk-partials][scale/shift 4096]
    const long floats = (long)(ws_size / sizeof(float));
    long avail = floats - (long)NCHUNK * PB - 4096;
    int nb = MAXNB;
    if ((long)nb * PB > avail) nb = (int)(avail / PB);
    if (nb < 1) nb = 1;
    const int chunk = (N + nb - 1) / nb;
    const int per   = (nb + NCHUNK - 1) / NCHUNK;

    float* ws2         = ws + (size_t)nb * PB;
    float* scale_shift = ws2 + (size_t)NCHUNK * PB;

    cbn_stats_kernel<<<nb, 256, 0, stream>>>(x, labels, ws, N, chunk);
    cbn_reduce_kernel<<<dim3((PB + 255) / 256, NCHUNK), 256, 0, stream>>>(ws, ws2, nb, per);
    cbn_finalize_kernel<<<8, 256, 0, stream>>>(ws2, gamma, beta, scale_shift);
    cbn_apply_kernel<<<2048, 256, 0, stream>>>(x, labels, scale_shift, y, N);
}